// Round 1
// baseline (5424.271 us; speedup 1.0000x reference)
//
#include <hip/hip_runtime.h>
#include <math.h>

#define HILB  4096
#define FEAT  256
#define OUTW  4098          // 4096 probs + entropy + entangle
#define GSTR  65            // planar G row stride in floats (odd -> conflict-free)

__device__ __forceinline__ float sanout(float v) {
    return (v == v && fabsf(v) < 1e30f) ? v : 1e6f;  // readable failure signature
}

__launch_bounds__(256, 4)
__global__ void qsp_kernel(const float* __restrict__ X,  const float* __restrict__ W1,
                           const float* __restrict__ B1, const float* __restrict__ W2,
                           const float* __restrict__ B2, const float* __restrict__ EP,
                           float* __restrict__ out)
{
    // planar Hermitian Gram: row stride 65 floats -> bank = (lane + j) % 32, conflict-free
    __shared__ float  GR[64 * GSTR];       // 16640 B
    __shared__ float  GI[64 * GSTR];       // 16640 B
    __shared__ float2 vc2[8][64];          // 8 rows of M staging (4096 B)
    __shared__ float2 v2c[64];             // Householder v broadcast
    __shared__ float2 w2c[64];             // Householder w broadcast
    __shared__ float  esq[64];             // |subdiag|^2 for Sturm
    __shared__ float  sx[FEAT];
    __shared__ float  sh[48];
    __shared__ float  T8[8];               // gate-chain product
    __shared__ float  red[4];
    __shared__ float  s_inv2;

    const int tid  = threadIdx.x;
    const int b    = blockIdx.x;
    const int lane = tid & 63;
    const int wv   = tid >> 6;

    // ---------- x row + h = tanh(x @ W1 + b1) ----------
    sx[tid] = X[b * FEAT + tid];
    __syncthreads();
    if (tid < 48) {
        float acc = B1[tid];
        for (int t = 0; t < FEAT; ++t) acc += sx[t] * W1[t * 48 + tid];
        sh[tid] = tanhf(acc);
    }
    // ---------- gate product T = R1*...*R33 (one thread of wave 1, overlaps) ----------
    if (tid == 64) {
        float t00r=1.f,t00i=0.f,t01r=0.f,t01i=0.f,t10r=0.f,t10i=0.f,t11r=1.f,t11i=0.f;
        for (int g = 0; g < 33; ++g) {
            int d = g / 11, q = g % 11;
            const float* p = EP + (d * 12 + q) * 4;
            float th = p[0], ph = p[1], la = p[2], ga = p[3];
            float c  = cosf(0.5f * th), sn = sinf(0.5f * th);
            float ephr = cosf(ph), ephi = sinf(ph);
            float elar = cosf(la), elai = sinf(la);
            float egar = cosf(ga), egai = sinf(ga);
            float r00r =  c,          r00i = 0.f;
            float r01r = -elar * sn,  r01i = -elai * sn;
            float r10r =  ephr * sn,  r10i =  ephi * sn;
            float r11r =  egar * c,   r11i =  egai * c;
            float n00r = t00r*r00r - t00i*r00i + t01r*r10r - t01i*r10i;
            float n00i = t00r*r00i + t00i*r00r + t01r*r10i + t01i*r10r;
            float n01r = t00r*r01r - t00i*r01i + t01r*r11r - t01i*r11i;
            float n01i = t00r*r01i + t00i*r01r + t01r*r11i + t01i*r11r;
            float n10r = t10r*r00r - t10i*r00i + t11r*r10r - t11i*r10i;
            float n10i = t10r*r00i + t10i*r00r + t11r*r10i + t11i*r10r;
            float n11r = t10r*r01r - t10i*r01i + t11r*r11r - t11i*r11i;
            float n11i = t10r*r01i + t10i*r01r + t11r*r11i + t11i*r11r;
            t00r=n00r; t00i=n00i; t01r=n01r; t01i=n01i;
            t10r=n10r; t10i=n10i; t11r=n11r; t11i=n11i;
        }
        T8[0]=t00r; T8[1]=t00i; T8[2]=t01r; T8[3]=t01i;
        T8[4]=t10r; T8[5]=t10i; T8[6]=t11r; T8[7]=t11i;
    }
    __syncthreads();

    // ---------- single pass: amps 8 rows at a time; probs -> registers; raw G; ssq ----------
    float accRe[16], accIm[16];
    float praw[16];                        // raw probs held in registers (static idx via unroll)
    #pragma unroll
    for (int jj = 0; jj < 16; ++jj) { accRe[jj] = 0.f; accIm[jj] = 0.f; }
    float ssq = 0.f;

    const int part = (tid >> 4) & 1;       // 0 = re, 1 = im
    const int lr   = tid >> 5;             // local row 0..7
    const int c0   = (tid & 15) * 4;       // 4 consecutive columns

    #pragma unroll
    for (int it = 0; it < 8; ++it) {
        int row = it * 8 + lr;
        int j0  = part * HILB + row * 64 + c0;
        float a0 = B2[j0], a1 = B2[j0+1], a2 = B2[j0+2], a3 = B2[j0+3];
        for (int k = 0; k < 48; ++k) {
            float4 w4 = *(const float4*)(W2 + k * 8192 + j0);
            float hk = sh[k];
            a0 += hk * w4.x; a1 += hk * w4.y;
            a2 += hk * w4.z; a3 += hk * w4.w;
        }
        float* vf = (float*)&vc2[lr][0];
        vf[(c0+0)*2 + part] = a0;
        vf[(c0+1)*2 + part] = a1;
        vf[(c0+2)*2 + part] = a2;
        vf[(c0+3)*2 + part] = a3;
        __syncthreads();

        if (it == 0) {                     // apply gate product T to raw psi0, psi1
            if (tid == 0) {
                float2 s0 = vc2[0][0], s1 = vc2[0][1];
                float n0r = s0.x*T8[0] - s0.y*T8[1] + s1.x*T8[4] - s1.y*T8[5];
                float n0i = s0.x*T8[1] + s0.y*T8[0] + s1.x*T8[5] + s1.y*T8[4];
                float n1r = s0.x*T8[2] - s0.y*T8[3] + s1.x*T8[6] - s1.y*T8[7];
                float n1i = s0.x*T8[3] + s0.y*T8[2] + s1.x*T8[7] + s1.y*T8[6];
                vc2[0][0] = make_float2(n0r, n0i);
                vc2[0][1] = make_float2(n1r, n1i);
            }
            __syncthreads();
        }

        // raw probs (512 per iteration) kept in registers; written once after norm
        #pragma unroll
        for (int s = 0; s < 2; ++s) {
            int jo  = tid + s * 256;
            int lr2 = jo >> 6, cc = jo & 63;
            float2 v = vc2[lr2][cc];
            float p  = v.x * v.x + v.y * v.y;
            praw[it * 2 + s] = p;
            ssq += p;
        }

        // raw G accumulation: thread owns rows p = wv*16..wv*16+15, column q = lane
        for (int rr = 0; rr < 8; ++rr) {
            float2 vq = vc2[rr][lane];
            #pragma unroll
            for (int jj = 0; jj < 16; ++jj) {
                float2 vp = vc2[rr][wv * 16 + jj];
                accRe[jj] += vp.x * vq.x + vp.y * vq.y;   // Re(conj(vp)*vq)
                accIm[jj] += vp.x * vq.y - vp.y * vq.x;   // Im(conj(vp)*vq)
            }
        }
        __syncthreads();
    }

    // ---------- norm reduction -> inv2, entropy ----------
    {
        float v = ssq;
        #pragma unroll
        for (int off = 32; off; off >>= 1) v += __shfl_down(v, off, 64);
        if (lane == 0) red[wv] = v;
        __syncthreads();
        if (tid == 0) {
            float tot = red[0] + red[1] + red[2] + red[3];
            float nrm = sqrtf(tot);
            float inv = 1.f / fmaxf(nrm, 1e-12f);
            float i2  = inv * inv;
            s_inv2 = i2;
            float n2  = tot * i2;
            float lam = fmaxf(n2, 1e-12f);
            out[(size_t)b * OUTW + HILB] = sanout(-lam * logf(lam) + 1.1314877e-7f);
        }
        __syncthreads();
    }
    const float inv2 = s_inv2;

    // publish scaled G (planar, conflict-free: bank = (p + lane) % 32)
    #pragma unroll
    for (int jj = 0; jj < 16; ++jj) {
        int p = wv * 16 + jj;
        GR[p * GSTR + lane] = inv2 * accRe[jj];
        GI[p * GSTR + lane] = inv2 * accIm[jj];
    }

    // scaled probs: single write, no global RMW
    #pragma unroll
    for (int i = 0; i < 16; ++i) {
        out[(size_t)b * OUTW + (i >> 1) * 512 + (i & 1) * 256 + tid] = sanout(inv2 * praw[i]);
    }

    __syncthreads();                       // G fully published; waves 1-3 done
    if (wv != 0) return;

    // ================= wave-synchronous eigensolve (wave 0 only, no barriers) ============
    // lane <-> matrix row. All G traffic is lane-private rows; cross-lane data (v, w)
    // goes through v2c/w2c broadcast slots. DS ops within one wave complete in order.
    const int ib = lane * GSTR;

    for (int k = 0; k < 62; ++k) {
        const int a = k + 1;

        // phase A: column norm, tau, v (v kept in registers, broadcast via LDS)
        float gr = 0.f, gi = 0.f;
        if (lane >= a) { gr = GR[ib + k]; gi = GI[ib + k]; }
        float sig = gr * gr + gi * gi;
        #pragma unroll
        for (int off = 1; off < 64; off <<= 1) sig += __shfl_xor(sig, off, 64);
        float x1r = __shfl(gr, a, 64);
        float x1i = __shfl(gi, a, 64);
        float ax1 = sqrtf(x1r * x1r + x1i * x1i);
        float nrm = sqrtf(sig);
        float tau = 0.f, pr = 1.f, pi = 0.f;
        if (sig > 1e-30f) {
            tau = 1.f / (sig + nrm * ax1);
            if (ax1 > 1e-30f) { pr = x1r / ax1; pi = x1i / ax1; }
        }
        float vr = gr, vi = gi;
        if (lane == a) { vr += pr * nrm; vi += pi * nrm; }   // v1 = x1 - alpha
        if (lane < a)  { vr = 0.f; vi = 0.f; }
        v2c[lane] = make_float2(vr, vi);
        if (lane == 0) esq[a] = sig;
        __builtin_amdgcn_wave_barrier();

        // phase B: p_i = tau * sum_j G[i][j] v[j]   (row i = lane, v[j] broadcast)
        float pxr = 0.f, pxi = 0.f;
        if (lane >= a) {
            #pragma unroll 4
            for (int j = a; j < 64; ++j) {
                float grj = GR[ib + j], gij = GI[ib + j];
                float2 vj = v2c[j];
                pxr += grj * vj.x - gij * vj.y;
                pxi += grj * vj.y + gij * vj.x;
            }
            pxr *= tau; pxi *= tau;
        }

        // phase C: K = (tau/2) Re(v^H p) ; w = p - K v
        float kp = vr * pxr + vi * pxi;
        #pragma unroll
        for (int off = 1; off < 64; off <<= 1) kp += __shfl_xor(kp, off, 64);
        float K  = 0.5f * tau * kp;
        float wr = pxr - K * vr, wi = pxi - K * vi;          // zero for lane < a
        w2c[lane] = make_float2(wr, wi);
        __builtin_amdgcn_wave_barrier();

        // phase D: rank-2 update G -= v w^H + w v^H on [a..63]^2 (own row in regs)
        if (lane >= a) {
            #pragma unroll 4
            for (int j = a; j < 64; ++j) {
                float2 vj = v2c[j], wj = w2c[j];
                float grj = GR[ib + j], gij = GI[ib + j];
                grj -= vr * wj.x + vi * wj.y + wr * vj.x + wi * vj.y;
                gij -= vi * wj.x - vr * wj.y + wi * vj.x - wr * vj.y;
                GR[ib + j] = grj; GI[ib + j] = gij;
            }
        }
        __builtin_amdgcn_wave_barrier();
    }

    if (lane == 0) {
        float gx = GR[63 * GSTR + 62], gy = GI[63 * GSTR + 62];
        esq[63] = gx * gx + gy * gy;
        esq[0]  = 0.f;
    }
    __builtin_amdgcn_wave_barrier();

    // ---------- Sturm bisection: lane t finds t-th smallest eigenvalue ----------
    {
        float lo = -0.02f, hi = 1.02f;      // PSD, trace 1 => spectrum in [0,1]
        for (int itb = 0; itb < 30; ++itb) {
            float mid = 0.5f * (lo + hi);
            int cnt = 0;
            float q = GR[0] - mid;          // d[0]
            cnt += (q < 0.f);
            for (int i = 1; i < 64; ++i) {
                float qp = q;
                float aq = (fabsf(qp) < 1e-18f) ? copysignf(1e-18f, qp) : qp;
                q = GR[i * GSTR + i] - mid - __fdividef(esq[i], aq);
                cnt += (q < 0.f);
            }
            if (cnt > lane) hi = mid; else lo = mid;
        }
        float lam  = fmaxf(0.5f * (lo + hi), 1e-24f);
        float term = -lam * logf(lam);
        #pragma unroll
        for (int off = 32; off; off >>= 1) term += __shfl_down(term, off, 64);
        if (lane == 0) out[(size_t)b * OUTW + HILB + 1] = sanout(term);
    }
}

extern "C" void kernel_launch(void* const* d_in, const int* in_sizes, int n_in,
                              void* d_out, int out_size, void* d_ws, size_t ws_size,
                              hipStream_t stream) {
    const float* X  = (const float*)d_in[0];
    const float* W1 = (const float*)d_in[1];
    const float* B1 = (const float*)d_in[2];
    const float* W2 = (const float*)d_in[3];
    const float* B2 = (const float*)d_in[4];
    const float* EP = (const float*)d_in[5];
    qsp_kernel<<<dim3(4096), dim3(256), 0, stream>>>(X, W1, B1, W2, B2, EP, (float*)d_out);
}

// Round 2
// 2127.965 us; speedup vs baseline: 2.5490x; 2.5490x over previous
//
#include <hip/hip_runtime.h>
#include <math.h>

#define HILB  4096
#define FEAT  256
#define OUTW  4098          // 4096 probs + entropy + entangle
#define GSTR  65            // planar G row stride in floats (odd -> conflict-free)

__device__ __forceinline__ float sanout(float v) {
    return (v == v && fabsf(v) < 1e30f) ? v : 1e6f;  // readable failure signature
}

__launch_bounds__(256, 4)
__global__ void qsp_kernel(const float* __restrict__ X,  const float* __restrict__ W1,
                           const float* __restrict__ B1, const float* __restrict__ W2,
                           const float* __restrict__ B2, const float* __restrict__ EP,
                           float* __restrict__ out)
{
    // planar Hermitian Gram: row stride 65 floats -> bank = (lane + j) % 32, conflict-free
    __shared__ float  GR[64 * GSTR];       // 16640 B
    __shared__ float  GI[64 * GSTR];       // 16640 B
    __shared__ float2 vc2[8][64];          // 8 rows of M staging (4096 B)
    __shared__ float2 v2c[64];             // Householder v broadcast
    __shared__ float2 w2c[64];             // Householder w broadcast
    __shared__ float  esq[64];             // |subdiag|^2 for Sturm
    __shared__ float  sx[FEAT];
    __shared__ float  sh[48];
    __shared__ float  T8[8];               // gate-chain product
    __shared__ float  red[4];
    __shared__ float  s_inv2;

    const int tid  = threadIdx.x;
    const int b    = blockIdx.x;
    const int lane = tid & 63;
    const int wv   = tid >> 6;

    // ---------- x row + h = tanh(x @ W1 + b1) ----------
    sx[tid] = X[b * FEAT + tid];
    __syncthreads();
    if (tid < 48) {
        float acc = B1[tid];
        for (int t = 0; t < FEAT; ++t) acc += sx[t] * W1[t * 48 + tid];
        sh[tid] = tanhf(acc);
    }
    // ---------- gate product T = R1*...*R33 (one thread of wave 1, overlaps) ----------
    if (tid == 64) {
        float t00r=1.f,t00i=0.f,t01r=0.f,t01i=0.f,t10r=0.f,t10i=0.f,t11r=1.f,t11i=0.f;
        for (int g = 0; g < 33; ++g) {
            int d = g / 11, q = g % 11;
            const float* p = EP + (d * 12 + q) * 4;
            float th = p[0], ph = p[1], la = p[2], ga = p[3];
            float c  = cosf(0.5f * th), sn = sinf(0.5f * th);
            float ephr = cosf(ph), ephi = sinf(ph);
            float elar = cosf(la), elai = sinf(la);
            float egar = cosf(ga), egai = sinf(ga);
            float r00r =  c,          r00i = 0.f;
            float r01r = -elar * sn,  r01i = -elai * sn;
            float r10r =  ephr * sn,  r10i =  ephi * sn;
            float r11r =  egar * c,   r11i =  egai * c;
            float n00r = t00r*r00r - t00i*r00i + t01r*r10r - t01i*r10i;
            float n00i = t00r*r00i + t00i*r00r + t01r*r10i + t01i*r10r;
            float n01r = t00r*r01r - t00i*r01i + t01r*r11r - t01i*r11i;
            float n01i = t00r*r01i + t00i*r01r + t01r*r11i + t01i*r11r;
            float n10r = t10r*r00r - t10i*r00i + t11r*r10r - t11i*r10i;
            float n10i = t10r*r00i + t10i*r00r + t11r*r10i + t11i*r10r;
            float n11r = t10r*r01r - t10i*r01i + t11r*r11r - t11i*r11i;
            float n11i = t10r*r01i + t10i*r01r + t11r*r11i + t11i*r11r;
            t00r=n00r; t00i=n00i; t01r=n01r; t01i=n01i;
            t10r=n10r; t10i=n10i; t11r=n11r; t11i=n11i;
        }
        T8[0]=t00r; T8[1]=t00i; T8[2]=t01r; T8[3]=t01i;
        T8[4]=t10r; T8[5]=t10i; T8[6]=t11r; T8[7]=t11i;
    }
    __syncthreads();

    // ---------- single pass: amps 8 rows at a time; RAW probs out; RAW G; ssq ----------
    float accRe[16], accIm[16];
    #pragma unroll
    for (int jj = 0; jj < 16; ++jj) { accRe[jj] = 0.f; accIm[jj] = 0.f; }
    float ssq = 0.f;

    const int part = (tid >> 4) & 1;       // 0 = re, 1 = im
    const int lr   = tid >> 5;             // local row 0..7
    const int c0   = (tid & 15) * 4;       // 4 consecutive columns

    for (int it = 0; it < 8; ++it) {
        int row = it * 8 + lr;
        int j0  = part * HILB + row * 64 + c0;
        float a0 = B2[j0], a1 = B2[j0+1], a2 = B2[j0+2], a3 = B2[j0+3];
        for (int k = 0; k < 48; ++k) {
            float4 w4 = *(const float4*)(W2 + k * 8192 + j0);
            float hk = sh[k];
            a0 += hk * w4.x; a1 += hk * w4.y;
            a2 += hk * w4.z; a3 += hk * w4.w;
        }
        float* vf = (float*)&vc2[lr][0];
        vf[(c0+0)*2 + part] = a0;
        vf[(c0+1)*2 + part] = a1;
        vf[(c0+2)*2 + part] = a2;
        vf[(c0+3)*2 + part] = a3;
        __syncthreads();

        if (it == 0) {                     // apply gate product T to raw psi0, psi1
            if (tid == 0) {
                float2 s0 = vc2[0][0], s1 = vc2[0][1];
                float n0r = s0.x*T8[0] - s0.y*T8[1] + s1.x*T8[4] - s1.y*T8[5];
                float n0i = s0.x*T8[1] + s0.y*T8[0] + s1.x*T8[5] + s1.y*T8[4];
                float n1r = s0.x*T8[2] - s0.y*T8[3] + s1.x*T8[6] - s1.y*T8[7];
                float n1i = s0.x*T8[3] + s0.y*T8[2] + s1.x*T8[7] + s1.y*T8[6];
                vc2[0][0] = make_float2(n0r, n0i);
                vc2[0][1] = make_float2(n1r, n1i);
            }
            __syncthreads();
        }

        // raw probs (512 per iteration); rescaled in-place after norm is known
        #pragma unroll
        for (int s = 0; s < 2; ++s) {
            int jo  = tid + s * 256;
            int lr2 = jo >> 6, cc = jo & 63;
            float2 v = vc2[lr2][cc];
            float praw = v.x * v.x + v.y * v.y;
            out[(size_t)b * OUTW + it * 512 + jo] = praw;
            ssq += praw;
        }

        // raw G accumulation: thread owns rows p = wv*16..wv*16+15, column q = lane
        for (int rr = 0; rr < 8; ++rr) {
            float2 vq = vc2[rr][lane];
            #pragma unroll
            for (int jj = 0; jj < 16; ++jj) {
                float2 vp = vc2[rr][wv * 16 + jj];
                accRe[jj] += vp.x * vq.x + vp.y * vq.y;   // Re(conj(vp)*vq)
                accIm[jj] += vp.x * vq.y - vp.y * vq.x;   // Im(conj(vp)*vq)
            }
        }
        __syncthreads();
    }

    // ---------- norm reduction -> inv2, entropy ----------
    {
        float v = ssq;
        #pragma unroll
        for (int off = 32; off; off >>= 1) v += __shfl_down(v, off, 64);
        if (lane == 0) red[wv] = v;
        __syncthreads();
        if (tid == 0) {
            float tot = red[0] + red[1] + red[2] + red[3];
            float nrm = sqrtf(tot);
            float inv = 1.f / fmaxf(nrm, 1e-12f);
            float i2  = inv * inv;
            s_inv2 = i2;
            float n2  = tot * i2;
            float lam = fmaxf(n2, 1e-12f);
            out[(size_t)b * OUTW + HILB] = sanout(-lam * logf(lam) + 1.1314877e-7f);
        }
        __syncthreads();
    }
    const float inv2 = s_inv2;

    // rescale this thread's own prob slots (same-thread RAW on global, no fence needed)
    #pragma unroll
    for (int i = 0; i < 16; ++i) {
        size_t idx = (size_t)b * OUTW + (i >> 1) * 512 + (i & 1) * 256 + tid;
        out[idx] = sanout(inv2 * out[idx]);
    }

    // publish scaled G (planar, conflict-free: bank = (p + lane) % 32)
    #pragma unroll
    for (int jj = 0; jj < 16; ++jj) {
        int p = wv * 16 + jj;
        GR[p * GSTR + lane] = inv2 * accRe[jj];
        GI[p * GSTR + lane] = inv2 * accIm[jj];
    }
    __syncthreads();                       // G fully published; waves 1-3 done
    if (wv != 0) return;

    // ================= wave-synchronous eigensolve (wave 0 only, no barriers) ============
    // lane <-> matrix row. All G traffic is lane-private rows; cross-lane data (v, w)
    // goes through v2c/w2c broadcast slots. DS ops within one wave complete in order.
    const int ib = lane * GSTR;

    for (int k = 0; k < 62; ++k) {
        const int a = k + 1;

        // phase A: column norm, tau, v (v kept in registers, broadcast via LDS)
        float gr = 0.f, gi = 0.f;
        if (lane >= a) { gr = GR[ib + k]; gi = GI[ib + k]; }
        float sig = gr * gr + gi * gi;
        #pragma unroll
        for (int off = 1; off < 64; off <<= 1) sig += __shfl_xor(sig, off, 64);
        float x1r = __shfl(gr, a, 64);
        float x1i = __shfl(gi, a, 64);
        float ax1 = sqrtf(x1r * x1r + x1i * x1i);
        float nrm = sqrtf(sig);
        float tau = 0.f, pr = 1.f, pi = 0.f;
        if (sig > 1e-30f) {
            tau = 1.f / (sig + nrm * ax1);
            if (ax1 > 1e-30f) { pr = x1r / ax1; pi = x1i / ax1; }
        }
        float vr = gr, vi = gi;
        if (lane == a) { vr += pr * nrm; vi += pi * nrm; }   // v1 = x1 - alpha
        if (lane < a)  { vr = 0.f; vi = 0.f; }
        v2c[lane] = make_float2(vr, vi);
        if (lane == 0) esq[a] = sig;
        __builtin_amdgcn_wave_barrier();

        // phase B: p_i = tau * sum_j G[i][j] v[j]   (row i = lane, v[j] broadcast)
        float pxr = 0.f, pxi = 0.f;
        if (lane >= a) {
            for (int j = a; j < 64; ++j) {
                float grj = GR[ib + j], gij = GI[ib + j];
                float2 vj = v2c[j];
                pxr += grj * vj.x - gij * vj.y;
                pxi += grj * vj.y + gij * vj.x;
            }
            pxr *= tau; pxi *= tau;
        }

        // phase C: K = (tau/2) Re(v^H p) ; w = p - K v
        float kp = vr * pxr + vi * pxi;
        #pragma unroll
        for (int off = 1; off < 64; off <<= 1) kp += __shfl_xor(kp, off, 64);
        float K  = 0.5f * tau * kp;
        float wr = pxr - K * vr, wi = pxi - K * vi;          // zero for lane < a
        w2c[lane] = make_float2(wr, wi);
        __builtin_amdgcn_wave_barrier();

        // phase D: rank-2 update G -= v w^H + w v^H on [a..63]^2 (own row in regs)
        if (lane >= a) {
            for (int j = a; j < 64; ++j) {
                float2 vj = v2c[j], wj = w2c[j];
                float grj = GR[ib + j], gij = GI[ib + j];
                grj -= vr * wj.x + vi * wj.y + wr * vj.x + wi * vj.y;
                gij -= vi * wj.x - vr * wj.y + wi * vj.x - wr * vj.y;
                GR[ib + j] = grj; GI[ib + j] = gij;
            }
        }
        __builtin_amdgcn_wave_barrier();
    }

    if (lane == 0) {
        float gx = GR[63 * GSTR + 62], gy = GI[63 * GSTR + 62];
        esq[63] = gx * gx + gy * gy;
        esq[0]  = 0.f;
    }
    __builtin_amdgcn_wave_barrier();

    // ---------- Sturm bisection: lane t finds t-th smallest eigenvalue ----------
    {
        float lo = -0.02f, hi = 1.02f;      // PSD, trace 1 => spectrum in [0,1]
        for (int itb = 0; itb < 30; ++itb) {
            float mid = 0.5f * (lo + hi);
            int cnt = 0;
            float q = GR[0] - mid;          // d[0]
            cnt += (q < 0.f);
            for (int i = 1; i < 64; ++i) {
                float qp = q;
                float aq = (fabsf(qp) < 1e-18f) ? copysignf(1e-18f, qp) : qp;
                q = GR[i * GSTR + i] - mid - __fdividef(esq[i], aq);
                cnt += (q < 0.f);
            }
            if (cnt > lane) hi = mid; else lo = mid;
        }
        float lam  = fmaxf(0.5f * (lo + hi), 1e-24f);
        float term = -lam * logf(lam);
        #pragma unroll
        for (int off = 32; off; off >>= 1) term += __shfl_down(term, off, 64);
        if (lane == 0) out[(size_t)b * OUTW + HILB + 1] = sanout(term);
    }
}

extern "C" void kernel_launch(void* const* d_in, const int* in_sizes, int n_in,
                              void* d_out, int out_size, void* d_ws, size_t ws_size,
                              hipStream_t stream) {
    const float* X  = (const float*)d_in[0];
    const float* W1 = (const float*)d_in[1];
    const float* B1 = (const float*)d_in[2];
    const float* W2 = (const float*)d_in[3];
    const float* B2 = (const float*)d_in[4];
    const float* EP = (const float*)d_in[5];
    qsp_kernel<<<dim3(4096), dim3(256), 0, stream>>>(X, W1, B1, W2, B2, EP, (float*)d_out);
}